// Round 1
// baseline (8954.251 us; speedup 1.0000x reference)
//
#include <hip/hip_runtime.h>
#include <math.h>

// Problem constants (fixed by setup_inputs)
constexpr int cA  = 128000;   // atoms
constexpr int cNM = 4000;     // molecules
constexpr int cE  = 256000;   // real edges
constexpr int cEA = cE + cA;  // edges + self loops
constexpr int cN  = 100000;   // nodes
constexpr int cM  = 50000;    // hyperedges
constexpr int cP  = 400000;   // pairs
constexpr int cNT = 80000;    // test rows
constexpr int cNTRAIN = 20000;

// ---------- small helpers ----------
__device__ __forceinline__ unsigned fmap(float f){
  unsigned u = __float_as_uint(f);
  return (u & 0x80000000u) ? ~u : (u | 0x80000000u);
}
__device__ __forceinline__ float funmap(unsigned u){
  unsigned v = (u & 0x80000000u) ? (u & 0x7fffffffu) : ~u;
  return __uint_as_float(v);
}

__global__ void k_fill(float* p, float v, int n){
  int i = blockIdx.x*256 + threadIdx.x; if (i < n) p[i] = v;
}
__global__ void k_count(const int* __restrict__ idx, float* cnt, int n){
  int i = blockIdx.x*256 + threadIdx.x; if (i < n) atomicAdd(&cnt[idx[i]], 1.f);
}
__global__ void k_rsqrt(float* p, int n){
  int i = blockIdx.x*256 + threadIdx.x; if (i < n) p[i] = rsqrtf(p[i]);
}
__global__ void k_recip_clamp(float* p, int n){
  int i = blockIdx.x*256 + threadIdx.x; if (i < n) p[i] = 1.f / fmaxf(p[i], 1.f);
}
__global__ void k_relu(float* p, int n){
  int i = blockIdx.x*256 + threadIdx.x; if (i < n) p[i] = fmaxf(p[i], 0.f);
}
__global__ void k_ycopy(const int* __restrict__ y, float* out){
  int i = blockIdx.x*256 + threadIdx.x; if (i < cNT) out[i] = (float)y[i];
}

// ---------- GCN ----------
__global__ void k_gcn_init(const float* __restrict__ xw, const float* __restrict__ dinv,
                           const float* __restrict__ b, float* __restrict__ out){
  int idx = blockIdx.x*256 + threadIdx.x;        // cA*64 threads
  int i = idx >> 6, j = idx & 63;
  float di = dinv[i];
  out[idx] = di*di*xw[idx] + b[j];
}
__global__ __launch_bounds__(256) void k_gcn_scatter(
    const int* __restrict__ src, const int* __restrict__ dst,
    const float* __restrict__ dinv, const float* __restrict__ xw, float* out){
  int e = blockIdx.x*4 + (threadIdx.x >> 6);
  if (e >= cE) return;
  int j = threadIdx.x & 63;
  int s = src[e], d = dst[e];
  float coef = dinv[s]*dinv[d];
  atomicAdd(&out[(size_t)d*64 + j], coef * xw[(size_t)s*64 + j]);
}

// ---------- GAT ----------
__global__ __launch_bounds__(256) void k_gat_al(
    const float* __restrict__ xh, const float* __restrict__ asrc,
    const float* __restrict__ adst, float* als, float* ald){
  int node = blockIdx.x*4 + (threadIdx.x >> 6);
  int lane = threadIdx.x & 63;
  int i0 = lane*4;
  float4 v = *reinterpret_cast<const float4*>(&xh[(size_t)node*256 + i0]);
  float s = v.x*asrc[i0] + v.y*asrc[i0+1] + v.z*asrc[i0+2] + v.w*asrc[i0+3];
  float d = v.x*adst[i0] + v.y*adst[i0+1] + v.z*adst[i0+2] + v.w*adst[i0+3];
  #pragma unroll
  for (int off = 1; off < 32; off <<= 1){
    s += __shfl_xor(s, off, 64);
    d += __shfl_xor(d, off, 64);
  }
  if ((lane & 31) == 0){
    int h = lane >> 5;
    als[node*2 + h] = s; ald[node*2 + h] = d;
  }
}
__global__ void k_gat_emx(const int* __restrict__ src, const int* __restrict__ dst,
                          const float* __restrict__ als, const float* __restrict__ ald,
                          float* ebuf, unsigned* mxu){
  int e = blockIdx.x*256 + threadIdx.x; if (e >= cEA) return;
  int s, d;
  if (e < cE){ s = src[e]; d = dst[e]; } else { s = e - cE; d = s; }
  float e0 = als[s*2]   + ald[d*2];   e0 = e0 > 0.f ? e0 : 0.2f*e0;
  float e1 = als[s*2+1] + ald[d*2+1]; e1 = e1 > 0.f ? e1 : 0.2f*e1;
  ebuf[e*2] = e0; ebuf[e*2+1] = e1;
  atomicMax(&mxu[d*2],   fmap(e0));
  atomicMax(&mxu[d*2+1], fmap(e1));
}
__global__ void k_gat_ps(const int* __restrict__ src, const int* __restrict__ dst,
                         float* ebuf, const unsigned* __restrict__ mxu, float* ssum){
  int e = blockIdx.x*256 + threadIdx.x; if (e >= cEA) return;
  int d;
  if (e < cE){ d = dst[e]; } else { d = e - cE; }
  float m0 = funmap(mxu[d*2]), m1 = funmap(mxu[d*2+1]);
  float p0 = expf(ebuf[e*2] - m0), p1 = expf(ebuf[e*2+1] - m1);
  ebuf[e*2] = p0; ebuf[e*2+1] = p1;
  atomicAdd(&ssum[d*2], p0); atomicAdd(&ssum[d*2+1], p1);
}
__global__ __launch_bounds__(256) void k_gat_scatter(
    const int* __restrict__ src, const int* __restrict__ dst,
    const float* __restrict__ ebuf, const float* __restrict__ ssum,
    const float* __restrict__ xh, float* g){
  int e = blockIdx.x*4 + (threadIdx.x >> 6);
  if (e >= cEA) return;
  int lane = threadIdx.x & 63;
  int s, d;
  if (e < cE){ s = src[e]; d = dst[e]; } else { s = e - cE; d = s; }
  int h = lane >> 5;
  float alpha = ebuf[e*2 + h] / ssum[d*2 + h];
  int col = lane*4;
  float4 v = *reinterpret_cast<const float4*>(&xh[(size_t)s*256 + col]);
  float* gp = &g[(size_t)d*256 + col];
  atomicAdd(gp+0, alpha*v.x); atomicAdd(gp+1, alpha*v.y);
  atomicAdd(gp+2, alpha*v.z); atomicAdd(gp+3, alpha*v.w);
}
__global__ __launch_bounds__(256) void k_mol_pool(
    const float* __restrict__ g, const float* __restrict__ gatb, float* matrix){
  int m = blockIdx.x, j = threadIdx.x;
  const float* gp = g + (size_t)m*32*256 + j;
  float s = 0.f;
  #pragma unroll 8
  for (int r = 0; r < 32; ++r) s += gp[r*256];
  matrix[(size_t)m*256 + j] = s*(1.f/32.f) + gatb[j];
}

// ---------- hypergraph v2v ----------
__global__ void k_count_pairs(const int* __restrict__ pv, const int* __restrict__ pe,
                              float* dv, float* de){
  int i = blockIdx.x*256 + threadIdx.x;
  if (i < cP){ atomicAdd(&dv[pv[i]], 1.f); atomicAdd(&de[pe[i]], 1.f); }
}
__global__ __launch_bounds__(256) void k_sc_edge(
    const int* __restrict__ pv, const int* __restrict__ pe,
    const float* __restrict__ X, float* efeat){
  int p = blockIdx.x*4 + (threadIdx.x >> 6);
  int lane = threadIdx.x & 63, col = lane*4;
  int v = pv[p], e = pe[p];
  float4 x = *reinterpret_cast<const float4*>(&X[(size_t)v*256 + col]);
  float* ep = &efeat[(size_t)e*256 + col];
  atomicAdd(ep+0, x.x); atomicAdd(ep+1, x.y); atomicAdd(ep+2, x.z); atomicAdd(ep+3, x.w);
}
__global__ __launch_bounds__(256) void k_sc_vert(
    const int* __restrict__ pv, const int* __restrict__ pe,
    const float* __restrict__ efeat, const float* __restrict__ rde, float* out){
  int p = blockIdx.x*4 + (threadIdx.x >> 6);
  int lane = threadIdx.x & 63, col = lane*4;
  int v = pv[p], e = pe[p];
  float w = rde[e];
  float4 x = *reinterpret_cast<const float4*>(&efeat[(size_t)e*256 + col]);
  float* op = &out[(size_t)v*256 + col];
  atomicAdd(op+0, w*x.x); atomicAdd(op+1, w*x.y); atomicAdd(op+2, w*x.z); atomicAdd(op+3, w*x.w);
}
__global__ void k_fin_relu(float* X, const float* __restrict__ rdv){
  int idx = blockIdx.x*256 + threadIdx.x;     // cN*64 float4 chunks
  int v = idx >> 6;
  float w = rdv[v];
  float4* p = reinterpret_cast<float4*>(X) + idx;
  float4 x = *p;
  x.x = fmaxf(x.x*w, 0.f); x.y = fmaxf(x.y*w, 0.f);
  x.z = fmaxf(x.z*w, 0.f); x.w = fmaxf(x.w*w, 0.f);
  *p = x;
}
__global__ void k_fin_fo(float* fo, const float* __restrict__ rdv,
                         const int* __restrict__ n2m, const float* __restrict__ matrix){
  int idx = blockIdx.x*256 + threadIdx.x;     // cN*64 float4 chunks
  int v = idx >> 6;
  float w = rdv[v];
  float4 mf = reinterpret_cast<const float4*>(matrix)[(size_t)n2m[v]*64 + (idx & 63)];
  float4* p = reinterpret_cast<float4*>(fo) + idx;
  float4 x = *p;
  x.x = x.x*w + mf.x; x.y = x.y*w + mf.y; x.z = x.z*w + mf.z; x.w = x.w*w + mf.w;
  *p = x;
}

// ---------- logits head ----------
__global__ __launch_bounds__(64) void k_logits(
    const float* __restrict__ z, const float* __restrict__ w3, const float* __restrict__ b3,
    const float* __restrict__ gamma, const float* __restrict__ beta,
    const float* __restrict__ wc, const float* __restrict__ bc, float* logits){
  __shared__ float zr[64];
  __shared__ float h3[64];
  int r = blockIdx.x, j = threadIdx.x;
  zr[j] = z[(size_t)r*64 + j];
  __syncthreads();
  float acc = 0.f;
  #pragma unroll 16
  for (int k = 0; k < 64; ++k) acc += zr[k]*w3[k*64 + j];
  acc += b3[j];
  acc = acc * (gamma[j] / sqrtf(1.f + 1e-5f)) + beta[j];
  h3[j] = fmaxf(acc, 0.f);
  __syncthreads();
  if (j < 3){
    float a = 0.f;
    for (int k = 0; k < 64; ++k) a += h3[k]*wc[k*3 + j];
    logits[(size_t)r*3 + j] = a + bc[j];
  }
}

// ---------- fp32 GEMMs: C = act(A@W + bias [+ onehot row]) ----------
// gemm64: BM=BN=64, BK=16, 256 thr, 4x4/thread. For N=64 outputs.
template<int ACT, bool ONEHOT>
__global__ __launch_bounds__(256) void gemm64(
    const float* __restrict__ Am, const float* __restrict__ W,
    const float* __restrict__ bias, const float* __restrict__ ohw,
    const int* __restrict__ ohidx, float* __restrict__ C, float* __restrict__ C2,
    int M, int K, int N){
  __shared__ float As[16][68];
  __shared__ float Ws[16][64];
  const int tid = threadIdx.x;
  const int bm = blockIdx.y << 6, bn = blockIdx.x << 6;
  const int tx = tid & 15, ty = tid >> 4;
  const int arow = tid >> 2, akk = (tid & 3) << 2;
  const int wrow = tid >> 4, wnn = (tid & 15) << 2;
  const int garow = bm + arow;
  const bool aok = garow < M;
  const float* ap = Am + (size_t)garow*K + akk;
  const float* wp = W + (size_t)wrow*N + bn + wnn;
  float acc[4][4] = {};
  for (int k0 = 0; k0 < K; k0 += 16){
    float4 av = make_float4(0.f,0.f,0.f,0.f);
    if (aok) av = *reinterpret_cast<const float4*>(ap + k0);
    As[akk+0][arow] = av.x; As[akk+1][arow] = av.y;
    As[akk+2][arow] = av.z; As[akk+3][arow] = av.w;
    float4 wv = *reinterpret_cast<const float4*>(wp + (size_t)k0*N);
    Ws[wrow][wnn+0] = wv.x; Ws[wrow][wnn+1] = wv.y;
    Ws[wrow][wnn+2] = wv.z; Ws[wrow][wnn+3] = wv.w;
    __syncthreads();
    #pragma unroll
    for (int k = 0; k < 16; ++k){
      float a0=As[k][(ty<<2)+0], a1=As[k][(ty<<2)+1], a2=As[k][(ty<<2)+2], a3=As[k][(ty<<2)+3];
      float b0=Ws[k][(tx<<2)+0], b1=Ws[k][(tx<<2)+1], b2=Ws[k][(tx<<2)+2], b3=Ws[k][(tx<<2)+3];
      acc[0][0]+=a0*b0; acc[0][1]+=a0*b1; acc[0][2]+=a0*b2; acc[0][3]+=a0*b3;
      acc[1][0]+=a1*b0; acc[1][1]+=a1*b1; acc[1][2]+=a1*b2; acc[1][3]+=a1*b3;
      acc[2][0]+=a2*b0; acc[2][1]+=a2*b1; acc[2][2]+=a2*b2; acc[2][3]+=a2*b3;
      acc[3][0]+=a3*b0; acc[3][1]+=a3*b1; acc[3][2]+=a3*b2; acc[3][3]+=a3*b3;
    }
    __syncthreads();
  }
  #pragma unroll
  for (int i = 0; i < 4; ++i){
    int gr = bm + (ty<<2) + i;
    if (gr >= M) break;
    const float* ohrow = ONEHOT ? (ohw + (size_t)ohidx[gr]*N) : nullptr;
    size_t rb = (size_t)gr*N + bn + (tx<<2);
    #pragma unroll
    for (int j = 0; j < 4; ++j){
      int gc = bn + (tx<<2) + j;
      float v = acc[i][j];
      if (bias) v += bias[gc];
      if (ONEHOT) v += ohrow[gc];
      if (ACT == 1) v = fmaxf(v, 0.f);
      else if (ACT == 2) v = 1.f/(1.f + expf(-v));
      C[rb + j] = v;
      if (C2) C2[rb + j] = v;
    }
  }
}

// gemm128: BM=BN=128, BK=8, 256 thr, 8x8/thread. For N multiple of 128.
template<int ACT, bool ONEHOT>
__global__ __launch_bounds__(256) void gemm128(
    const float* __restrict__ Am, const float* __restrict__ W,
    const float* __restrict__ bias, const float* __restrict__ ohw,
    const int* __restrict__ ohidx, float* __restrict__ C, float* __restrict__ C2,
    int M, int K, int N){
  __shared__ float As[8][132];
  __shared__ float Ws[8][128];
  const int tid = threadIdx.x;
  const int bm = blockIdx.y << 7, bn = blockIdx.x << 7;
  const int tx = tid & 15, ty = tid >> 4;
  const int arow = tid >> 1, akk = (tid & 1) << 2;
  const int wrow = tid >> 5, wnn = (tid & 31) << 2;
  const int garow = bm + arow;
  const bool aok = garow < M;
  const float* ap = Am + (size_t)garow*K + akk;
  const float* wp = W + (size_t)wrow*N + bn + wnn;
  float acc[8][8] = {};
  for (int k0 = 0; k0 < K; k0 += 8){
    float4 av = make_float4(0.f,0.f,0.f,0.f);
    if (aok) av = *reinterpret_cast<const float4*>(ap + k0);
    As[akk+0][arow] = av.x; As[akk+1][arow] = av.y;
    As[akk+2][arow] = av.z; As[akk+3][arow] = av.w;
    float4 wv = *reinterpret_cast<const float4*>(wp + (size_t)k0*N);
    *reinterpret_cast<float4*>(&Ws[wrow][wnn]) = wv;
    __syncthreads();
    #pragma unroll
    for (int k = 0; k < 8; ++k){
      float a[8], b[8];
      #pragma unroll
      for (int t = 0; t < 4; ++t){
        a[t]   = As[k][(ty<<3)+t];   a[t+4] = As[k][(ty<<3)+4+t];
        b[t]   = Ws[k][(tx<<3)+t];   b[t+4] = Ws[k][(tx<<3)+4+t];
      }
      #pragma unroll
      for (int i = 0; i < 8; ++i)
        #pragma unroll
        for (int j = 0; j < 8; ++j) acc[i][j] += a[i]*b[j];
    }
    __syncthreads();
  }
  #pragma unroll
  for (int i = 0; i < 8; ++i){
    int gr = bm + (ty<<3) + i;
    if (gr >= M) break;
    const float* ohrow = ONEHOT ? (ohw + (size_t)ohidx[gr]*N) : nullptr;
    size_t rb = (size_t)gr*N + bn + (tx<<3);
    #pragma unroll
    for (int j = 0; j < 8; ++j){
      int gc = bn + (tx<<3) + j;
      float v = acc[i][j];
      if (bias) v += bias[gc];
      if (ONEHOT) v += ohrow[gc];
      if (ACT == 1) v = fmaxf(v, 0.f);
      else if (ACT == 2) v = 1.f/(1.f + expf(-v));
      C[rb + j] = v;
      if (C2) C2[rb + j] = v;
    }
  }
}

extern "C" void kernel_launch(void* const* d_in, const int* in_sizes, int n_in,
                              void* d_out, int out_size, void* d_ws, size_t ws_size,
                              hipStream_t stream){
  const float* atom_x  = (const float*)d_in[0];
  const float* gcn_w   = (const float*)d_in[1];
  const float* gcn_b   = (const float*)d_in[2];
  const float* gat_w   = (const float*)d_in[3];
  const float* gat_as  = (const float*)d_in[4];
  const float* gat_ad  = (const float*)d_in[5];
  const float* gat_b   = (const float*)d_in[6];
  const float* feature = (const float*)d_in[7];
  const float* th1_w   = (const float*)d_in[8];
  const float* th1_b   = (const float*)d_in[9];
  const float* th2_w   = (const float*)d_in[10];
  const float* th2_b   = (const float*)d_in[11];
  const float* fc_mu_w = (const float*)d_in[12];
  const float* fc_mu_b = (const float*)d_in[13];
  const float* fc_lv_w = (const float*)d_in[14];
  const float* fc_lv_b = (const float*)d_in[15];
  const float* lin3_w  = (const float*)d_in[16];
  const float* lin3_b  = (const float*)d_in[17];
  const float* bn3_g   = (const float*)d_in[18];
  const float* bn3_b   = (const float*)d_in[19];
  const float* cls_w   = (const float*)d_in[20];
  const float* cls_b   = (const float*)d_in[21];
  const float* dec_w1  = (const float*)d_in[22];
  const float* dec_b1  = (const float*)d_in[23];
  const float* dec_w2  = (const float*)d_in[24];
  const float* dec_b2  = (const float*)d_in[25];
  const int* eidx      = (const int*)d_in[27];
  const int* src = eidx;
  const int* dst = eidx + cE;
  const int* node2mol  = (const int*)d_in[29];
  const int* pair_v    = (const int*)d_in[30];
  const int* pair_e    = (const int*)d_in[31];
  const int* y_target  = (const int*)d_in[32];

  float* out  = (float*)d_out;
  float* o_mu = out;                    // 80000*64
  float* o_lv = out + 5120000;
  float* o_z  = out + 10240000;
  float* o_lg = out + 15360000;         // 80000*3
  float* o_xr = out + 15600000;         // 80000*512
  float* o_y  = out + 56560000;         // 80000
  float* o_fo = out + 56640000;         // 100000*256

  float* ws   = (float*)d_ws;
  // stage-aliased pool (lifetimes disjoint)
  float* xw   = ws;                     // A*64   (stage 1)
  float* h    = ws + 8192000;           // A*64   (stage 1-2)
  float* g    = ws + 16384000;          // A*256  (stage 2-3)
  float* X1   = ws;                     // N*256  (stage 4)
  float* X2   = ws + 25600000;          // N*256  (stage 4)
  float* hdec = ws;                     // 80000*512 (stage 5)
  float* pers = ws + 51200000;
  float* dinv   = pers;                 // 128000 (deg -> rsqrt in place)
  float* als    = pers + 128000;        // A*2
  float* ald    = pers + 384000;        // A*2
  unsigned* mxu = (unsigned*)(pers + 640000);   // A*2
  float* ssum   = pers + 896000;        // A*2
  float* ebuf   = pers + 1152000;       // (E+A)*2
  float* matrix = pers + 1920000;       // 4000*256
  float* rde    = pers + 2944000;       // M
  float* rdv    = pers + 2994000;       // N
  // d_out-aliased scratch (dead before final stage writes those slots)
  float* xh    = o_xr;                  // A*256 fits in x_reconst slot
  float* efeat = o_mu;                  // M*256 fits in mu+lv+z slots

  // ---- Stage 1: GCN ----
  k_fill<<<cA/256, 256, 0, stream>>>(dinv, 1.f, cA);          // self-loop deg
  k_count<<<cE/256, 256, 0, stream>>>(dst, dinv, cE);
  k_rsqrt<<<cA/256, 256, 0, stream>>>(dinv, cA);
  gemm64<0,false><<<dim3(1,2000), 256, 0, stream>>>(atom_x, gcn_w, nullptr, nullptr, nullptr,
                                                    xw, nullptr, cA, 48, 64);
  k_gcn_init<<<cA*64/256, 256, 0, stream>>>(xw, dinv, gcn_b, h);
  k_gcn_scatter<<<cE/4, 256, 0, stream>>>(src, dst, dinv, xw, h);
  k_relu<<<cA*64/256, 256, 0, stream>>>(h, cA*64);

  // ---- Stage 2: GAT ----
  gemm128<0,false><<<dim3(2,1000), 256, 0, stream>>>(h, gat_w, nullptr, nullptr, nullptr,
                                                     xh, nullptr, cA, 64, 256);
  k_gat_al<<<cA/4, 256, 0, stream>>>(xh, gat_as, gat_ad, als, ald);
  hipMemsetAsync(mxu, 0, (size_t)cA*2*sizeof(unsigned), stream);
  hipMemsetAsync(ssum, 0, (size_t)cA*2*sizeof(float), stream);
  k_gat_emx<<<cEA/256, 256, 0, stream>>>(src, dst, als, ald, ebuf, mxu);
  k_gat_ps<<<cEA/256, 256, 0, stream>>>(src, dst, ebuf, mxu, ssum);
  hipMemsetAsync(g, 0, (size_t)cA*256*sizeof(float), stream);
  k_gat_scatter<<<cEA/4, 256, 0, stream>>>(src, dst, ebuf, ssum, xh, g);
  k_mol_pool<<<cNM, 256, 0, stream>>>(g, gat_b, matrix);

  // ---- Stage 3/4: node MLPs + hypergraph conv ----
  hipMemsetAsync(rde, 0, (size_t)cM*sizeof(float), stream);
  hipMemsetAsync(rdv, 0, (size_t)cN*sizeof(float), stream);
  k_count_pairs<<<(cP+255)/256, 256, 0, stream>>>(pair_v, pair_e, rdv, rde);
  k_recip_clamp<<<(cM+255)/256, 256, 0, stream>>>(rde, cM);
  k_recip_clamp<<<(cN+255)/256, 256, 0, stream>>>(rdv, cN);

  gemm128<1,false><<<dim3(2,782), 256, 0, stream>>>(feature, th1_w, th1_b, nullptr, nullptr,
                                                    X1, nullptr, cN, 512, 256);
  hipMemsetAsync(efeat, 0, (size_t)cM*256*sizeof(float), stream);
  k_sc_edge<<<cP/4, 256, 0, stream>>>(pair_v, pair_e, X1, efeat);
  hipMemsetAsync(X2, 0, (size_t)cN*256*sizeof(float), stream);
  k_sc_vert<<<cP/4, 256, 0, stream>>>(pair_v, pair_e, efeat, rde, X2);
  k_fin_relu<<<cN*64/256, 256, 0, stream>>>(X2, rdv);

  gemm128<1,false><<<dim3(2,782), 256, 0, stream>>>(X2, th2_w, th2_b, nullptr, nullptr,
                                                    X1, nullptr, cN, 256, 256);
  hipMemsetAsync(efeat, 0, (size_t)cM*256*sizeof(float), stream);
  k_sc_edge<<<cP/4, 256, 0, stream>>>(pair_v, pair_e, X1, efeat);
  hipMemsetAsync(o_fo, 0, (size_t)cN*256*sizeof(float), stream);
  k_sc_vert<<<cP/4, 256, 0, stream>>>(pair_v, pair_e, efeat, rde, o_fo);
  k_fin_fo<<<cN*64/256, 256, 0, stream>>>(o_fo, rdv, node2mol, matrix);

  // ---- Stage 5: heads (y_bin one-hot folded in as per-row weight-row add) ----
  const float* ft = o_fo + (size_t)cNTRAIN*256;
  gemm64<0,true><<<dim3(1,1250), 256, 0, stream>>>(ft, fc_mu_w, fc_mu_b,
      fc_mu_w + 256*64, y_target, o_mu, o_z, cNT, 256, 64);
  gemm64<0,true><<<dim3(1,1250), 256, 0, stream>>>(ft, fc_lv_w, fc_lv_b,
      fc_lv_w + 256*64, y_target, o_lv, nullptr, cNT, 256, 64);
  k_logits<<<cNT, 64, 0, stream>>>(o_mu, lin3_w, lin3_b, bn3_g, bn3_b, cls_w, cls_b, o_lg);
  gemm128<1,true><<<dim3(4,625), 256, 0, stream>>>(o_mu, dec_w1, dec_b1,
      dec_w1 + 64*512, y_target, hdec, nullptr, cNT, 64, 512);
  gemm128<2,false><<<dim3(4,625), 256, 0, stream>>>(hdec, dec_w2, dec_b2, nullptr, nullptr,
      o_xr, nullptr, cNT, 512, 512);
  k_ycopy<<<(cNT+255)/256, 256, 0, stream>>>(y_target, o_y);
}

// Round 2
// 2703.996 us; speedup vs baseline: 3.3115x; 3.3115x over previous
//
#include <hip/hip_runtime.h>
#include <math.h>

// Problem constants (fixed by setup_inputs)
constexpr int cA  = 128000;   // atoms
constexpr int cNM = 4000;     // molecules
constexpr int cE  = 256000;   // real edges
constexpr int cEA = cE + cA;  // edges + self loops
constexpr int cN  = 100000;   // nodes
constexpr int cM  = 50000;    // hyperedges
constexpr int cP  = 400000;   // pairs
constexpr int cNT = 80000;    // test rows
constexpr int cNTRAIN = 20000;

// ---------- small helpers ----------
__global__ void k_ycopy(const int* __restrict__ y, float* out){
  int i = blockIdx.x*256 + threadIdx.x; if (i < cNT) out[i] = (float)y[i];
}

// ---------- CSR build: histogram -> inclusive scan -> backward fill ----------
__global__ void k_hist_pairs(const int* __restrict__ pv, const int* __restrict__ pe,
                             int* cntE, int* cntV){
  int i = blockIdx.x*256 + threadIdx.x;
  if (i < cP){ atomicAdd(&cntE[pe[i]], 1); atomicAdd(&cntV[pv[i]], 1); }
}
__global__ void k_hist_edges(const int* __restrict__ dst, int* cntD){
  int i = blockIdx.x*256 + threadIdx.x; if (i >= cEA) return;
  int d = (i < cE) ? dst[i] : (i - cE);
  atomicAdd(&cntD[d], 1);
}
__global__ void k_degrees(const int* __restrict__ cntE, const int* __restrict__ cntV,
                          const int* __restrict__ cntD,
                          float* rde, float* rdv, float* dinv){
  int i = blockIdx.x*256 + threadIdx.x;
  if (i < cM) rde[i]  = 1.f / fmaxf((float)cntE[i], 1.f);
  if (i < cN) rdv[i]  = 1.f / fmaxf((float)cntV[i], 1.f);
  if (i < cA) dinv[i] = rsqrtf((float)cntD[i]);   // >=1 (self loop)
}
__global__ void k_scan1(int* a, int n, int* bsum){
  __shared__ int s[256];
  int t = threadIdx.x, i = blockIdx.x*256 + t;
  s[t] = (i < n) ? a[i] : 0;
  __syncthreads();
  #pragma unroll
  for (int off = 1; off < 256; off <<= 1){
    int u = (t >= off) ? s[t-off] : 0;
    __syncthreads();
    s[t] += u;
    __syncthreads();
  }
  if (i < n) a[i] = s[t];
  if (t == 255) bsum[blockIdx.x] = s[255];
}
__global__ void k_scan2(int* a, int n){   // single block, n <= 512
  __shared__ int s[512];
  int t = threadIdx.x;
  s[t] = (t < n) ? a[t] : 0;
  __syncthreads();
  #pragma unroll
  for (int off = 1; off < 512; off <<= 1){
    int u = (t >= off) ? s[t-off] : 0;
    __syncthreads();
    s[t] += u;
    __syncthreads();
  }
  if (t < n) a[t] = s[t];
}
__global__ void k_scan3(int* a, int n, const int* __restrict__ bsum){
  int b = blockIdx.x, i = b*256 + threadIdx.x;
  if (b > 0 && i < n) a[i] += bsum[b-1];
}
// after fill, end arrays hold START offsets; bucket b spans [arr[b], arr[b+1]) (last: total)
__global__ void k_fill_pairs(const int* __restrict__ pv, const int* __restrict__ pe,
                             int* endE, int* endV, int* listE, int* listV){
  int i = blockIdx.x*256 + threadIdx.x; if (i >= cP) return;
  int v = pv[i], e = pe[i];
  int se = atomicSub(&endE[e], 1) - 1; listE[se] = v;   // store vertex directly
  int sv = atomicSub(&endV[v], 1) - 1; listV[sv] = e;   // store hyperedge directly
}
__global__ void k_fill_edges(const int* __restrict__ src, const int* __restrict__ dst,
                             int* endD, int* listD){
  int i = blockIdx.x*256 + threadIdx.x; if (i >= cEA) return;
  int s, d;
  if (i < cE){ s = src[i]; d = dst[i]; } else { s = d = i - cE; }
  int sl = atomicSub(&endD[d], 1) - 1; listD[sl] = s;   // store src atom directly
}

// ---------- GCN gather: h[d] = relu(dinv[d]*sum(dinv[s]*xw[s]) + b) ----------
__global__ __launch_bounds__(256) void k_gcn_gather(
    const int* __restrict__ start, const int* __restrict__ list,
    const float* __restrict__ xw, const float* __restrict__ dinv,
    const float* __restrict__ b, float* __restrict__ h){
  int d = blockIdx.x*4 + (threadIdx.x >> 6);
  int j = threadIdx.x & 63;
  int lo = start[d], hi = (d == cA-1) ? cEA : start[d+1];
  float acc = 0.f;
  for (int k = lo; k < hi; ++k){
    int s = list[k];
    acc += dinv[s] * xw[(size_t)s*64 + j];
  }
  h[(size_t)d*64 + j] = fmaxf(dinv[d]*acc + b[j], 0.f);
}

// ---------- GAT per-node attention logits ----------
__global__ __launch_bounds__(256) void k_gat_al(
    const float* __restrict__ xh, const float* __restrict__ asrc,
    const float* __restrict__ adst, float* als, float* ald){
  int node = blockIdx.x*4 + (threadIdx.x >> 6);
  int lane = threadIdx.x & 63;
  int i0 = lane*4;
  float4 v = *reinterpret_cast<const float4*>(&xh[(size_t)node*256 + i0]);
  float s = v.x*asrc[i0] + v.y*asrc[i0+1] + v.z*asrc[i0+2] + v.w*asrc[i0+3];
  float d = v.x*adst[i0] + v.y*adst[i0+1] + v.z*adst[i0+2] + v.w*adst[i0+3];
  #pragma unroll
  for (int off = 1; off < 32; off <<= 1){
    s += __shfl_xor(s, off, 64);
    d += __shfl_xor(d, off, 64);
  }
  if ((lane & 31) == 0){
    int h = lane >> 5;
    als[node*2 + h] = s; ald[node*2 + h] = d;
  }
}

// ---------- GAT gather (fused softmax over incoming edges) ----------
__global__ __launch_bounds__(256) void k_gat_gather(
    const int* __restrict__ start, const int* __restrict__ list,
    const float* __restrict__ als, const float* __restrict__ ald,
    const float* __restrict__ xh, float* __restrict__ g){
  int d = blockIdx.x*4 + (threadIdx.x >> 6);
  int lane = threadIdx.x & 63, col = lane*4, hh = lane >> 5;
  int lo = start[d], hi = (d == cA-1) ? cEA : start[d+1];
  float ad = ald[(size_t)d*2 + hh];
  float m = -1e30f;
  for (int k = lo; k < hi; ++k){
    int s = list[k];
    float v = als[(size_t)s*2 + hh] + ad;
    v = v > 0.f ? v : 0.2f*v;
    m = fmaxf(m, v);
  }
  float sum = 0.f;
  float4 acc = make_float4(0.f,0.f,0.f,0.f);
  for (int k = lo; k < hi; ++k){
    int s = list[k];
    float v = als[(size_t)s*2 + hh] + ad;
    v = v > 0.f ? v : 0.2f*v;
    float p = expf(v - m);
    sum += p;
    float4 x = *reinterpret_cast<const float4*>(&xh[(size_t)s*256 + col]);
    acc.x += p*x.x; acc.y += p*x.y; acc.z += p*x.z; acc.w += p*x.w;
  }
  float r = 1.f / sum;
  float4 o = make_float4(acc.x*r, acc.y*r, acc.z*r, acc.w*r);
  *reinterpret_cast<float4*>(&g[(size_t)d*256 + col]) = o;
}

__global__ __launch_bounds__(256) void k_mol_pool(
    const float* __restrict__ g, const float* __restrict__ gatb, float* matrix){
  int m = blockIdx.x, j = threadIdx.x;
  const float* gp = g + (size_t)m*32*256 + j;
  float s = 0.f;
  #pragma unroll 8
  for (int r = 0; r < 32; ++r) s += gp[r*256];
  matrix[(size_t)m*256 + j] = s*(1.f/32.f) + gatb[j];
}

// ---------- hypergraph gathers ----------
__global__ __launch_bounds__(256) void k_he_gather(
    const int* __restrict__ start, const int* __restrict__ list,
    const float* __restrict__ X, const float* __restrict__ rde, float* __restrict__ efeat){
  int e = blockIdx.x*4 + (threadIdx.x >> 6);
  int lane = threadIdx.x & 63, col = lane*4;
  int lo = start[e], hi = (e == cM-1) ? cP : start[e+1];
  float4 acc = make_float4(0.f,0.f,0.f,0.f);
  for (int k = lo; k < hi; ++k){
    int v = list[k];
    float4 x = *reinterpret_cast<const float4*>(&X[(size_t)v*256 + col]);
    acc.x += x.x; acc.y += x.y; acc.z += x.z; acc.w += x.w;
  }
  float w = rde[e];
  float4 o = make_float4(acc.x*w, acc.y*w, acc.z*w, acc.w*w);
  *reinterpret_cast<float4*>(&efeat[(size_t)e*256 + col]) = o;
}
// MODE 0: out = relu(acc*rdv)    MODE 1: out = acc*rdv + matrix[n2m[v]]
template<int MODE>
__global__ __launch_bounds__(256) void k_v_gather(
    const int* __restrict__ start, const int* __restrict__ list,
    const float* __restrict__ efeat, const float* __restrict__ rdv,
    const int* __restrict__ n2m, const float* __restrict__ matrix,
    float* __restrict__ out){
  int v = blockIdx.x*4 + (threadIdx.x >> 6);
  int lane = threadIdx.x & 63, col = lane*4;
  int lo = start[v], hi = (v == cN-1) ? cP : start[v+1];
  float4 acc = make_float4(0.f,0.f,0.f,0.f);
  for (int k = lo; k < hi; ++k){
    int e = list[k];
    float4 x = *reinterpret_cast<const float4*>(&efeat[(size_t)e*256 + col]);
    acc.x += x.x; acc.y += x.y; acc.z += x.z; acc.w += x.w;
  }
  float w = rdv[v];
  float4 o = make_float4(acc.x*w, acc.y*w, acc.z*w, acc.w*w);
  if (MODE == 0){
    o.x = fmaxf(o.x, 0.f); o.y = fmaxf(o.y, 0.f);
    o.z = fmaxf(o.z, 0.f); o.w = fmaxf(o.w, 0.f);
  } else {
    float4 mf = reinterpret_cast<const float4*>(matrix)[(size_t)n2m[v]*64 + lane];
    o.x += mf.x; o.y += mf.y; o.z += mf.z; o.w += mf.w;
  }
  *reinterpret_cast<float4*>(&out[(size_t)v*256 + col]) = o;
}

// ---------- logits head ----------
__global__ __launch_bounds__(64) void k_logits(
    const float* __restrict__ z, const float* __restrict__ w3, const float* __restrict__ b3,
    const float* __restrict__ gamma, const float* __restrict__ beta,
    const float* __restrict__ wc, const float* __restrict__ bc, float* logits){
  __shared__ float zr[64];
  __shared__ float h3[64];
  int r = blockIdx.x, j = threadIdx.x;
  zr[j] = z[(size_t)r*64 + j];
  __syncthreads();
  float acc = 0.f;
  #pragma unroll 16
  for (int k = 0; k < 64; ++k) acc += zr[k]*w3[k*64 + j];
  acc += b3[j];
  acc = acc * (gamma[j] / sqrtf(1.f + 1e-5f)) + beta[j];
  h3[j] = fmaxf(acc, 0.f);
  __syncthreads();
  if (j < 3){
    float a = 0.f;
    for (int k = 0; k < 64; ++k) a += h3[k]*wc[k*3 + j];
    logits[(size_t)r*3 + j] = a + bc[j];
  }
}

// ---------- fp32 GEMMs: C = act(A@W + bias [+ onehot row]) ----------
template<int ACT, bool ONEHOT>
__global__ __launch_bounds__(256) void gemm64(
    const float* __restrict__ Am, const float* __restrict__ W,
    const float* __restrict__ bias, const float* __restrict__ ohw,
    const int* __restrict__ ohidx, float* __restrict__ C, float* __restrict__ C2,
    int M, int K, int N){
  __shared__ float As[16][68];
  __shared__ float Ws[16][64];
  const int tid = threadIdx.x;
  const int bm = blockIdx.y << 6, bn = blockIdx.x << 6;
  const int tx = tid & 15, ty = tid >> 4;
  const int arow = tid >> 2, akk = (tid & 3) << 2;
  const int wrow = tid >> 4, wnn = (tid & 15) << 2;
  const int garow = bm + arow;
  const bool aok = garow < M;
  const float* ap = Am + (size_t)garow*K + akk;
  const float* wp = W + (size_t)wrow*N + bn + wnn;
  float acc[4][4] = {};
  for (int k0 = 0; k0 < K; k0 += 16){
    float4 av = make_float4(0.f,0.f,0.f,0.f);
    if (aok) av = *reinterpret_cast<const float4*>(ap + k0);
    As[akk+0][arow] = av.x; As[akk+1][arow] = av.y;
    As[akk+2][arow] = av.z; As[akk+3][arow] = av.w;
    float4 wv = *reinterpret_cast<const float4*>(wp + (size_t)k0*N);
    Ws[wrow][wnn+0] = wv.x; Ws[wrow][wnn+1] = wv.y;
    Ws[wrow][wnn+2] = wv.z; Ws[wrow][wnn+3] = wv.w;
    __syncthreads();
    #pragma unroll
    for (int k = 0; k < 16; ++k){
      float a0=As[k][(ty<<2)+0], a1=As[k][(ty<<2)+1], a2=As[k][(ty<<2)+2], a3=As[k][(ty<<2)+3];
      float b0=Ws[k][(tx<<2)+0], b1=Ws[k][(tx<<2)+1], b2=Ws[k][(tx<<2)+2], b3=Ws[k][(tx<<2)+3];
      acc[0][0]+=a0*b0; acc[0][1]+=a0*b1; acc[0][2]+=a0*b2; acc[0][3]+=a0*b3;
      acc[1][0]+=a1*b0; acc[1][1]+=a1*b1; acc[1][2]+=a1*b2; acc[1][3]+=a1*b3;
      acc[2][0]+=a2*b0; acc[2][1]+=a2*b1; acc[2][2]+=a2*b2; acc[2][3]+=a2*b3;
      acc[3][0]+=a3*b0; acc[3][1]+=a3*b1; acc[3][2]+=a3*b2; acc[3][3]+=a3*b3;
    }
    __syncthreads();
  }
  #pragma unroll
  for (int i = 0; i < 4; ++i){
    int gr = bm + (ty<<2) + i;
    if (gr >= M) break;
    const float* ohrow = ONEHOT ? (ohw + (size_t)ohidx[gr]*N) : nullptr;
    size_t rb = (size_t)gr*N + bn + (tx<<2);
    #pragma unroll
    for (int j = 0; j < 4; ++j){
      int gc = bn + (tx<<2) + j;
      float v = acc[i][j];
      if (bias) v += bias[gc];
      if (ONEHOT) v += ohrow[gc];
      if (ACT == 1) v = fmaxf(v, 0.f);
      else if (ACT == 2) v = 1.f/(1.f + expf(-v));
      C[rb + j] = v;
      if (C2) C2[rb + j] = v;
    }
  }
}

template<int ACT, bool ONEHOT>
__global__ __launch_bounds__(256) void gemm128(
    const float* __restrict__ Am, const float* __restrict__ W,
    const float* __restrict__ bias, const float* __restrict__ ohw,
    const int* __restrict__ ohidx, float* __restrict__ C, float* __restrict__ C2,
    int M, int K, int N){
  __shared__ float As[8][132];
  __shared__ float Ws[8][128];
  const int tid = threadIdx.x;
  const int bm = blockIdx.y << 7, bn = blockIdx.x << 7;
  const int tx = tid & 15, ty = tid >> 4;
  const int arow = tid >> 1, akk = (tid & 1) << 2;
  const int wrow = tid >> 5, wnn = (tid & 31) << 2;
  const int garow = bm + arow;
  const bool aok = garow < M;
  const float* ap = Am + (size_t)garow*K + akk;
  const float* wp = W + (size_t)wrow*N + bn + wnn;
  float acc[8][8] = {};
  for (int k0 = 0; k0 < K; k0 += 8){
    float4 av = make_float4(0.f,0.f,0.f,0.f);
    if (aok) av = *reinterpret_cast<const float4*>(ap + k0);
    As[akk+0][arow] = av.x; As[akk+1][arow] = av.y;
    As[akk+2][arow] = av.z; As[akk+3][arow] = av.w;
    float4 wv = *reinterpret_cast<const float4*>(wp + (size_t)k0*N);
    *reinterpret_cast<float4*>(&Ws[wrow][wnn]) = wv;
    __syncthreads();
    #pragma unroll
    for (int k = 0; k < 8; ++k){
      float a[8], b[8];
      #pragma unroll
      for (int t = 0; t < 4; ++t){
        a[t]   = As[k][(ty<<3)+t];   a[t+4] = As[k][(ty<<3)+4+t];
        b[t]   = Ws[k][(tx<<3)+t];   b[t+4] = Ws[k][(tx<<3)+4+t];
      }
      #pragma unroll
      for (int i = 0; i < 8; ++i)
        #pragma unroll
        for (int j = 0; j < 8; ++j) acc[i][j] += a[i]*b[j];
    }
    __syncthreads();
  }
  #pragma unroll
  for (int i = 0; i < 8; ++i){
    int gr = bm + (ty<<3) + i;
    if (gr >= M) break;
    const float* ohrow = ONEHOT ? (ohw + (size_t)ohidx[gr]*N) : nullptr;
    size_t rb = (size_t)gr*N + bn + (tx<<3);
    #pragma unroll
    for (int j = 0; j < 8; ++j){
      int gc = bn + (tx<<3) + j;
      float v = acc[i][j];
      if (bias) v += bias[gc];
      if (ONEHOT) v += ohrow[gc];
      if (ACT == 1) v = fmaxf(v, 0.f);
      else if (ACT == 2) v = 1.f/(1.f + expf(-v));
      C[rb + j] = v;
      if (C2) C2[rb + j] = v;
    }
  }
}

extern "C" void kernel_launch(void* const* d_in, const int* in_sizes, int n_in,
                              void* d_out, int out_size, void* d_ws, size_t ws_size,
                              hipStream_t stream){
  const float* atom_x  = (const float*)d_in[0];
  const float* gcn_w   = (const float*)d_in[1];
  const float* gcn_b   = (const float*)d_in[2];
  const float* gat_w   = (const float*)d_in[3];
  const float* gat_as  = (const float*)d_in[4];
  const float* gat_ad  = (const float*)d_in[5];
  const float* gat_b   = (const float*)d_in[6];
  const float* feature = (const float*)d_in[7];
  const float* th1_w   = (const float*)d_in[8];
  const float* th1_b   = (const float*)d_in[9];
  const float* th2_w   = (const float*)d_in[10];
  const float* th2_b   = (const float*)d_in[11];
  const float* fc_mu_w = (const float*)d_in[12];
  const float* fc_mu_b = (const float*)d_in[13];
  const float* fc_lv_w = (const float*)d_in[14];
  const float* fc_lv_b = (const float*)d_in[15];
  const float* lin3_w  = (const float*)d_in[16];
  const float* lin3_b  = (const float*)d_in[17];
  const float* bn3_g   = (const float*)d_in[18];
  const float* bn3_b   = (const float*)d_in[19];
  const float* cls_w   = (const float*)d_in[20];
  const float* cls_b   = (const float*)d_in[21];
  const float* dec_w1  = (const float*)d_in[22];
  const float* dec_b1  = (const float*)d_in[23];
  const float* dec_w2  = (const float*)d_in[24];
  const float* dec_b2  = (const float*)d_in[25];
  const int* eidx      = (const int*)d_in[27];
  const int* src = eidx;
  const int* dst = eidx + cE;
  const int* node2mol  = (const int*)d_in[29];
  const int* pair_v    = (const int*)d_in[30];
  const int* pair_e    = (const int*)d_in[31];
  const int* y_target  = (const int*)d_in[32];

  float* out  = (float*)d_out;
  float* o_mu = out;                    // 80000*64
  float* o_lv = out + 5120000;
  float* o_z  = out + 10240000;
  float* o_lg = out + 15360000;         // 80000*3
  float* o_xr = out + 15600000;         // 80000*512
  float* o_y  = out + 56560000;         // 80000
  float* o_fo = out + 56640000;         // 100000*256

  float* ws   = (float*)d_ws;
  // stage-aliased pool (lifetimes disjoint)
  float* xw   = ws;                     // A*64   (stage 1)
  float* h    = ws + 8192000;           // A*64   (stage 1-2)
  float* g    = ws + 16384000;          // A*256  (stage 2-3)
  float* X1   = ws;                     // N*256  (stage 4)
  float* X2   = ws + 25600000;          // N*256  (stage 4)
  float* hdec = ws;                     // 80000*512 (stage 5)
  // persistent region
  float* pers = ws + 51200000;
  float* dinv   = pers;                 // A
  float* als    = pers + 128000;        // A*2
  float* ald    = pers + 384000;        // A*2
  float* rde    = pers + 640000;        // M
  float* rdv    = pers + 690000;        // N
  int*   ib     = (int*)(pers + 790000);
  int* endE  = ib;                      // M   (counts -> scan -> starts)
  int* endV  = ib + 50000;              // N
  int* endD  = ib + 150000;             // A
  int* listE = ib + 278000;             // P  (stores pair_v)
  int* listV = ib + 678000;             // P  (stores pair_e)
  int* listD = ib + 1078000;            // E+A (stores src atom)
  int* bs0   = ib + 1462000;            // scan block sums
  int* bs1   = bs0 + 512;
  int* bs2   = bs0 + 1024;
  // d_out-aliased scratch (dead before final stage writes those slots)
  float* xh     = o_xr;                 // A*256 fits in x_reconst slot
  float* efeat  = o_mu;                 // M*256 fits in mu+lv+z slots
  float* matrix = o_xr + 33000000;      // NM*256, after xh, before dec2 write

  // ---- CSR build (endE/endV/endD contiguous -> one memset) ----
  hipMemsetAsync(endE, 0, (size_t)(50000+100000+128000)*sizeof(int), stream);
  k_hist_pairs<<<(cP+255)/256, 256, 0, stream>>>(pair_v, pair_e, endE, endV);
  k_hist_edges<<<(cEA+255)/256, 256, 0, stream>>>(dst, endD);
  k_degrees<<<(cA+255)/256, 256, 0, stream>>>(endE, endV, endD, rde, rdv, dinv);
  k_scan1<<<(cM+255)/256, 256, 0, stream>>>(endE, cM, bs0);
  k_scan1<<<(cN+255)/256, 256, 0, stream>>>(endV, cN, bs1);
  k_scan1<<<(cA+255)/256, 256, 0, stream>>>(endD, cA, bs2);
  k_scan2<<<1, 512, 0, stream>>>(bs0, (cM+255)/256);
  k_scan2<<<1, 512, 0, stream>>>(bs1, (cN+255)/256);
  k_scan2<<<1, 512, 0, stream>>>(bs2, (cA+255)/256);
  k_scan3<<<(cM+255)/256, 256, 0, stream>>>(endE, cM, bs0);
  k_scan3<<<(cN+255)/256, 256, 0, stream>>>(endV, cN, bs1);
  k_scan3<<<(cA+255)/256, 256, 0, stream>>>(endD, cA, bs2);
  k_fill_pairs<<<(cP+255)/256, 256, 0, stream>>>(pair_v, pair_e, endE, endV, listE, listV);
  k_fill_edges<<<(cEA+255)/256, 256, 0, stream>>>(src, dst, endD, listD);

  // ---- Stage 1: GCN ----
  gemm64<0,false><<<dim3(1,2000), 256, 0, stream>>>(atom_x, gcn_w, nullptr, nullptr, nullptr,
                                                    xw, nullptr, cA, 48, 64);
  k_gcn_gather<<<cA/4, 256, 0, stream>>>(endD, listD, xw, dinv, gcn_b, h);

  // ---- Stage 2: GAT ----
  gemm128<0,false><<<dim3(2,1000), 256, 0, stream>>>(h, gat_w, nullptr, nullptr, nullptr,
                                                     xh, nullptr, cA, 64, 256);
  k_gat_al<<<cA/4, 256, 0, stream>>>(xh, gat_as, gat_ad, als, ald);
  k_gat_gather<<<cA/4, 256, 0, stream>>>(endD, listD, als, ald, xh, g);
  k_mol_pool<<<cNM, 256, 0, stream>>>(g, gat_b, matrix);

  // ---- Stage 3/4: node MLPs + hypergraph conv ----
  gemm128<1,false><<<dim3(2,782), 256, 0, stream>>>(feature, th1_w, th1_b, nullptr, nullptr,
                                                    X1, nullptr, cN, 512, 256);
  k_he_gather<<<cM/4, 256, 0, stream>>>(endE, listE, X1, rde, efeat);
  k_v_gather<0><<<cN/4, 256, 0, stream>>>(endV, listV, efeat, rdv, nullptr, nullptr, X2);
  gemm128<1,false><<<dim3(2,782), 256, 0, stream>>>(X2, th2_w, th2_b, nullptr, nullptr,
                                                    X1, nullptr, cN, 256, 256);
  k_he_gather<<<cM/4, 256, 0, stream>>>(endE, listE, X1, rde, efeat);
  k_v_gather<1><<<cN/4, 256, 0, stream>>>(endV, listV, efeat, rdv, node2mol, matrix, o_fo);

  // ---- Stage 5: heads (y_bin one-hot folded in as per-row weight-row add) ----
  const float* ft = o_fo + (size_t)cNTRAIN*256;
  gemm64<0,true><<<dim3(1,1250), 256, 0, stream>>>(ft, fc_mu_w, fc_mu_b,
      fc_mu_w + 256*64, y_target, o_mu, o_z, cNT, 256, 64);
  gemm64<0,true><<<dim3(1,1250), 256, 0, stream>>>(ft, fc_lv_w, fc_lv_b,
      fc_lv_w + 256*64, y_target, o_lv, nullptr, cNT, 256, 64);
  k_logits<<<cNT, 64, 0, stream>>>(o_mu, lin3_w, lin3_b, bn3_g, bn3_b, cls_w, cls_b, o_lg);
  gemm128<1,true><<<dim3(4,625), 256, 0, stream>>>(o_mu, dec_w1, dec_b1,
      dec_w1 + 64*512, y_target, hdec, nullptr, cNT, 64, 512);
  gemm128<2,false><<<dim3(4,625), 256, 0, stream>>>(hdec, dec_w2, dec_b2, nullptr, nullptr,
      o_xr, nullptr, cNT, 512, 512);
  k_ycopy<<<(cNT+255)/256, 256, 0, stream>>>(y_target, o_y);
}